// Round 2
// baseline (490.206 us; speedup 1.0000x reference)
//
#include <hip/hip_runtime.h>
#include <math.h>

#define L2C   65536
#define NC    (2 * L2C)
#define FINC  8
#define FOUTC 8
#define KC    13
#define EPB   32          // edges per block
#define BLOCK 256         // 8 threads per edge (one per fout)

constexpr double E_D = 2.71828182845904523536;
constexpr float SCALE_F = (float)((2.0 + 2.0 * E_D) / (E_D - 1.0));

// d_ws layout: [0..255] mask-encoding flag (int at offset 0; 1 = 4-byte words,
//              0 = 1-byte bools); [256 ...] xt = x transposed to (N, FIN), 4 MiB.

// Detect mask element width on-device. For int32 (00 00 00 0/1 LE -> bytes
// 1..3 zero) and float32 (1.0f = 00 00 80 3f -> byte 1 zero) encodings, every
// byte at offset % 4 == 1 is zero. For a 1-byte bool mask those offsets hold
// random 0/1 values -> OR over 16384 samples is nonzero w.p. 1 - 2^-16384.
__global__ __launch_bounds__(256)
void detect_mask_kernel(const unsigned char* __restrict__ m, int* __restrict__ flag) {
    __shared__ int any_nz;
    if (threadIdx.x == 0) any_nz = 0;
    __syncthreads();
    int local = 0;
    for (int e = threadIdx.x; e < 16384; e += 256) {
        local |= m[(size_t)e * 4 + 1];
    }
    if (local) atomicOr(&any_nz, 1);
    __syncthreads();
    if (threadIdx.x == 0) flag[0] = (any_nz == 0) ? 1 : 0;
}

// x (FIN, N) -> xt (N, FIN): gathered column becomes 32 contiguous bytes.
__global__ __launch_bounds__(256)
void transpose_x_kernel(const float* __restrict__ x, float* __restrict__ xt) {
    int n = blockIdx.x * 256 + threadIdx.x;
    float v[FINC];
#pragma unroll
    for (int i = 0; i < FINC; ++i) v[i] = x[(size_t)i * NC + n];
    float4* dst = reinterpret_cast<float4*>(xt + ((size_t)n << 3));
    dst[0] = make_float4(v[0], v[1], v[2], v[3]);
    dst[1] = make_float4(v[4], v[5], v[6], v[7]);
}

__global__ __launch_bounds__(BLOCK)
void edge_conv_kernel(const float* __restrict__ xt,
                      const int* __restrict__ flag_p,
                      const float* __restrict__ Wh, const float* __restrict__ Wv,
                      const float* __restrict__ bh, const float* __restrict__ bv,
                      const unsigned char* __restrict__ mh,
                      const unsigned char* __restrict__ mv,
                      const int* __restrict__ kh, const int* __restrict__ kv,
                      float* __restrict__ out)
{
    // W reordered to [o][k][i], stride 108 floats per o -> the 8 distinct
    // ds_read_b128 addrs per instr land in disjoint bank quads (12*o mod 32).
    __shared__ float Wsh[FOUTC * 108];

    const int tid = threadIdx.x;
    const int el  = tid >> 3;   // edge within block
    const int o   = tid & 7;    // output channel

    const int blk = blockIdx.x;
    const int blocks_per_branch = L2C / EPB;   // 2048
    const bool hor = (blk < blocks_per_branch);

    const float*         W    = hor ? Wh  : Wv;
    const float*         bias = hor ? bh  : bv;
    const unsigned char* mask = hor ? mh  : mv;
    const int*           ker  = hor ? kh  : kv;
    const int bblk = hor ? blk : blk - blocks_per_branch;
    const int be   = bblk * EPB + el;          // edge index within branch
    const int col  = hor ? be : (be + L2C);    // hor_edge_lst = arange, vert = arange+L2

    const int words = flag_p[0];               // wave-uniform

    // Stage W (reordered) into LDS.
    for (int j = tid; j < FOUTC * FINC * KC; j += BLOCK) {
        int o2 = j / (FINC * KC);
        int r  = j % (FINC * KC);
        int i2 = r / KC;
        int k2 = r % KC;
        Wsh[o2 * 108 + k2 * 8 + i2] = W[j];
    }
    __syncthreads();

    // Kernel column indices (the 8 o-lanes of an edge share addresses).
    int cols[KC];
#pragma unroll
    for (int k = 0; k < KC; ++k) cols[k] = ker[(size_t)be * KC + k];

    // Build the (edge, o) mask row as a 104-bit register bitmask, bit j = i*13+k.
    unsigned long long b0 = 0, b1 = 0;
    if (words) {
        // 4-byte elements (int32 0/1 or float32 0.0/1.0): nonzero word == true.
        const uint4* mrow = reinterpret_cast<const uint4*>(
            reinterpret_cast<const unsigned int*>(mask) + (size_t)be * 832 + (size_t)o * 104);
#pragma unroll
        for (int j4 = 0; j4 < 26; ++j4) {
            uint4 v = mrow[j4];
            unsigned long long nz =
                (v.x ? 1ull : 0ull) | (v.y ? 2ull : 0ull) |
                (v.z ? 4ull : 0ull) | (v.w ? 8ull : 0ull);
            int j = j4 * 4;
            if (j < 64) b0 |= nz << j;
            else        b1 |= nz << (j - 64);
        }
    } else {
        // 1-byte bools: 104 bytes = 13 aligned ulongs.
        const unsigned long long* mp =
            reinterpret_cast<const unsigned long long*>(mask) + (size_t)be * 104 + (size_t)o * 13;
#pragma unroll
        for (int q = 0; q < 13; ++q) {
            unsigned long long w8 = mp[q];     // 8 bytes, each 0 or 1
#pragma unroll
            for (int c = 0; c < 8; ++c) {
                unsigned long long bit = (w8 >> (c * 8)) & 1ull;
                int j = q * 8 + c;
                if (j < 64) b0 |= bit << j;
                else if (j < 104) b1 |= bit << (j - 64);
            }
        }
    }

    float acc = bias[o];

#pragma unroll
    for (int k = 0; k < KC; ++k) {
        const int c = cols[k];
        const float4* xp = reinterpret_cast<const float4*>(xt + ((size_t)c << 3));
        float4 a = xp[0], b4 = xp[1];
        float xv[8] = {a.x, a.y, a.z, a.w, b4.x, b4.y, b4.z, b4.w};
        const float4 w0 = *reinterpret_cast<const float4*>(&Wsh[o * 108 + k * 8]);
        const float4 w1 = *reinterpret_cast<const float4*>(&Wsh[o * 108 + k * 8 + 4]);
        float wv[8] = {w0.x, w0.y, w0.z, w0.w, w1.x, w1.y, w1.z, w1.w};
#pragma unroll
        for (int i = 0; i < FINC; ++i) {
            const int mb = i * KC + k;
            unsigned long long on = (mb < 64) ? (b0 >> mb) : (b1 >> (mb - 64));
            if (on & 1ull) acc = fmaf(wv[i], xv[i], acc);
        }
    }

    const float sig = 1.0f / (1.0f + __expf(-acc));
    out[(size_t)o * NC + col] = (sig - 0.5f) * SCALE_F;
}

extern "C" void kernel_launch(void* const* d_in, const int* in_sizes, int n_in,
                              void* d_out, int out_size, void* d_ws, size_t ws_size,
                              hipStream_t stream) {
    const float*         x   = (const float*)d_in[0];
    const float*         Wh  = (const float*)d_in[1];
    const float*         Wv  = (const float*)d_in[2];
    const float*         bh  = (const float*)d_in[3];
    const float*         bv  = (const float*)d_in[4];
    const unsigned char* mh  = (const unsigned char*)d_in[5];
    const unsigned char* mv  = (const unsigned char*)d_in[6];
    const int*           kh  = (const int*)d_in[7];
    const int*           kv  = (const int*)d_in[8];
    float* out  = (float*)d_out;
    int*   flag = (int*)d_ws;
    float* xt   = (float*)((char*)d_ws + 256);

    detect_mask_kernel<<<1, 256, 0, stream>>>(mh, flag);
    transpose_x_kernel<<<NC / 256, 256, 0, stream>>>(x, xt);
    edge_conv_kernel<<<(2 * L2C) / EPB, BLOCK, 0, stream>>>(
        xt, flag, Wh, Wv, bh, bv, mh, mv, kh, kv, out);
}

// Round 3
// 454.706 us; speedup vs baseline: 1.0781x; 1.0781x over previous
//
#include <hip/hip_runtime.h>
#include <math.h>

#define L2C   65536
#define NC    (2 * L2C)
#define FINC  8
#define FOUTC 8
#define KC    13
#define BLOCK 256         // 4 waves = 4 edges per block
#define EPB   4

constexpr double E_D = 2.71828182845904523536;
constexpr float SCALE_F = (float)((2.0 + 2.0 * E_D) / (E_D - 1.0));

// d_ws: [0..255] mask-encoding flag (1 = 4-byte words, 0 = 1-byte bools);
//       [256...] xt = x transposed to (N, FIN), 4 MiB.

// For 4-byte encodings (int32 0/1: bytes 1..3 zero; float32 1.0f = 00 00 80 3f:
// byte 1 zero) every byte at offset%4==1 is 0. For 1-byte bools those offsets
// are random 0/1 -> OR over 4096 samples nonzero w.p. 1-2^-4096.
__global__ __launch_bounds__(256)
void detect_mask_kernel(const unsigned char* __restrict__ m, int* __restrict__ flag) {
    __shared__ int any_nz;
    if (threadIdx.x == 0) any_nz = 0;
    __syncthreads();
    int local = 0;
    for (int e = threadIdx.x; e < 4096; e += 256) local |= m[(size_t)e * 4 + 1];
    if (local) atomicOr(&any_nz, 1);
    __syncthreads();
    if (threadIdx.x == 0) flag[0] = (any_nz == 0) ? 1 : 0;
}

// x (FIN, N) -> xt (N, FIN): a gathered column becomes one 32 B segment.
__global__ __launch_bounds__(256)
void transpose_x_kernel(const float* __restrict__ x, float* __restrict__ xt) {
    int n = blockIdx.x * 256 + threadIdx.x;
    float v[FINC];
#pragma unroll
    for (int i = 0; i < FINC; ++i) v[i] = x[(size_t)i * NC + n];
    float4* dst = reinterpret_cast<float4*>(xt + ((size_t)n << 3));
    dst[0] = make_float4(v[0], v[1], v[2], v[3]);
    dst[1] = make_float4(v[4], v[5], v[6], v[7]);
}

// One wave per edge. lane = o*8 + i. Mask words for the edge are 832
// contiguous dwords -> 13 fully-coalesced dword loads + __ballot bit-packing.
__global__ __launch_bounds__(BLOCK)
void edge_conv_kernel(const float* __restrict__ xt,
                      const int* __restrict__ flag_p,
                      const float* __restrict__ Wh, const float* __restrict__ Wv,
                      const float* __restrict__ bh, const float* __restrict__ bv,
                      const unsigned char* __restrict__ mh,
                      const unsigned char* __restrict__ mv,
                      const int* __restrict__ kh, const int* __restrict__ kv,
                      float* __restrict__ out)
{
    __shared__ float Wsh[FOUTC * FINC * KC];   // [o][i][k], same flat order as input

    const int tid  = threadIdx.x;
    const int lane = tid & 63;
    const int wv_i = tid >> 6;                 // wave (edge) within block
    const int o    = lane >> 3;
    const int i    = lane & 7;

    const int blk = blockIdx.x;
    const int blocks_per_branch = L2C / EPB;   // 16384
    const bool hor = (blk < blocks_per_branch);

    const float*         W    = hor ? Wh  : Wv;
    const float*         bias = hor ? bh  : bv;
    const unsigned char* mask = hor ? mh  : mv;
    const int*           ker  = hor ? kh  : kv;
    const int bblk = hor ? blk : blk - blocks_per_branch;
    const int be   = bblk * EPB + wv_i;        // edge index within branch
    const int col  = hor ? be : (be + L2C);    // edge lists are arange / arange+L2

    const int words = flag_p[0];               // grid-uniform

    // Stage W into LDS (identical flat layout).
    for (int j = tid; j < FOUTC * FINC * KC; j += BLOCK) Wsh[j] = W[j];
    __syncthreads();

    // ---- mask bits for this lane: bits k=0..12 of (o,i) row ----
    unsigned int mbits;
    if (words) {
        const unsigned int* mw = reinterpret_cast<const unsigned int*>(mask)
                                 + (size_t)be * 832;
        unsigned long long myb = 0;            // lane t (t<13) keeps ballot t
#pragma unroll
        for (int t = 0; t < 13; ++t) {
            unsigned int w = mw[t * 64 + lane];          // coalesced
            unsigned long long bal = __ballot(w != 0u);  // bit l = word t*64+l
            if (lane == t) myb = bal;
        }
        const int s     = lane * 13;           // flat bit offset of this row
        const int u0    = s >> 6;              // 0..12
        const int shift = s & 63;
        unsigned long long lo = __shfl(myb, u0);
        unsigned long long hi = __shfl(myb, u0 + 1);     // lane 13 -> myb=0, safe
        unsigned int bits = (unsigned int)(lo >> shift);
        if (shift) bits |= (unsigned int)(hi << (64 - shift));
        mbits = bits & 0x1FFFu;
    } else {
        const unsigned char* mrow = mask + (size_t)be * 832 + (size_t)lane * 13;
        unsigned int bits = 0;
#pragma unroll
        for (int k = 0; k < 13; ++k) bits |= (mrow[k] ? 1u : 0u) << k;
        mbits = bits;
    }

    // ---- gather columns (wave-uniform) and x values ----
    int cols[KC];
#pragma unroll
    for (int k = 0; k < KC; ++k) cols[k] = ker[(size_t)be * KC + k];

    float acc = 0.0f;
#pragma unroll
    for (int k = 0; k < KC; ++k) {
        float xv = xt[((size_t)cols[k] << 3) + i];       // one 32 B seg / wave / k
        float wk = Wsh[lane * KC + k];                   // 2-way LDS alias: free
        float wm = (mbits >> k) & 1u ? wk : 0.0f;
        acc = fmaf(wm, xv, acc);
    }

    // ---- reduce over i (lanes o*8 .. o*8+7) ----
    acc += __shfl_xor(acc, 1);
    acc += __shfl_xor(acc, 2);
    acc += __shfl_xor(acc, 4);

    if (i == 0) {
        float z   = acc + bias[o];
        float sig = 1.0f / (1.0f + __expf(-z));
        out[(size_t)o * NC + col] = (sig - 0.5f) * SCALE_F;
    }
}

extern "C" void kernel_launch(void* const* d_in, const int* in_sizes, int n_in,
                              void* d_out, int out_size, void* d_ws, size_t ws_size,
                              hipStream_t stream) {
    const float*         x   = (const float*)d_in[0];
    const float*         Wh  = (const float*)d_in[1];
    const float*         Wv  = (const float*)d_in[2];
    const float*         bh  = (const float*)d_in[3];
    const float*         bv  = (const float*)d_in[4];
    const unsigned char* mh  = (const unsigned char*)d_in[5];
    const unsigned char* mv  = (const unsigned char*)d_in[6];
    const int*           kh  = (const int*)d_in[7];
    const int*           kv  = (const int*)d_in[8];
    float* out  = (float*)d_out;
    int*   flag = (int*)d_ws;
    float* xt   = (float*)((char*)d_ws + 256);

    detect_mask_kernel<<<1, 256, 0, stream>>>(mh, flag);
    transpose_x_kernel<<<NC / 256, 256, 0, stream>>>(x, xt);
    edge_conv_kernel<<<(2 * L2C) / EPB, BLOCK, 0, stream>>>(
        xt, flag, Wh, Wv, bh, bv, mh, mv, kh, kv, out);
}